// Round 7
// baseline (361.661 us; speedup 1.0000x reference)
//
#include <hip/hip_runtime.h>
#include <hip/hip_bf16.h>

// DotAttention: B=64, S=4096, H=1024, f32 inputs, f32 outputs.
// out layout (flat f32): [B, 2H] concat(context, dec)  then  [B, S] weights.
//
// Fused single-kernel: per (b,chunk) block computes its online-softmax partial,
// release-fences, bumps a per-batch counter; the last block of each batch
// acquire-fences and finalizes that batch (context/dec/weights). NT loads on
// the 1 GB read-once enc stream. Fallback: proven two-kernel path if ws tight.

#define NB 64
#define NS 4096
#define NH 1024
#define NC 16
#define NTHREADS 256
#define NWAVES 4
#define ROWS (NS / NC)                 // 256 rows per chunk
#define PSTRIDE (NH + 2)               // ctx[NH], m, l

typedef float f32x4 __attribute__((ext_vector_type(4)));

__device__ __forceinline__ f32x4 nt_load4(const float* p) {
    return __builtin_nontemporal_load(reinterpret_cast<const f32x4*>(p));
}

// ---------------- fused kernel ----------------
__global__ __launch_bounds__(NTHREADS)
void dotattn_fused(const float* __restrict__ enc, const float* __restrict__ dec,
                   float* __restrict__ scores, float* __restrict__ partials,
                   int* __restrict__ counters, float* __restrict__ out)
{
    const int blk   = blockIdx.x;
    const int b     = blk >> 4;        // / NC
    const int chunk = blk & (NC - 1);
    const int tid   = threadIdx.x;
    const int lane  = tid & 63;
    const int wave  = tid >> 6;

    // Lane owns h-slice {lane*4 + k*256 + j : k,j in 0..3} (16 of 1024).
    const float* decb = dec + b * NH;
    f32x4 dreg[4];
#pragma unroll
    for (int k = 0; k < 4; ++k)
        dreg[k] = *reinterpret_cast<const f32x4*>(decb + lane * 4 + k * 256);

    f32x4 ctx[4];
#pragma unroll
    for (int k = 0; k < 4; ++k) ctx[k] = (f32x4){0.f, 0.f, 0.f, 0.f};
    float m = -3.0e38f, l = 0.f;

    const int start = chunk * ROWS;
    const float* encb = enc + (size_t)b * NS * NH;

    // prefetch first row for this wave (non-temporal: read-once stream)
    f32x4 en[4];
    {
        const size_t base = (size_t)(start + wave) * NH + lane * 4;
#pragma unroll
        for (int k = 0; k < 4; ++k)
            en[k] = nt_load4(encb + base + k * 256);
    }

    for (int s = start + wave; s < start + ROWS; s += NWAVES) {
        f32x4 e[4];
#pragma unroll
        for (int k = 0; k < 4; ++k) e[k] = en[k];

        if (s + NWAVES < start + ROWS) {            // prefetch next row
            const size_t nbase = (size_t)(s + NWAVES) * NH + lane * 4;
#pragma unroll
            for (int k = 0; k < 4; ++k)
                en[k] = nt_load4(encb + nbase + k * 256);
        }

        f32x4 p4 = e[0] * dreg[0];
#pragma unroll
        for (int k = 1; k < 4; ++k) p4 += e[k] * dreg[k];
        float p = p4.x + p4.y + p4.z + p4.w;
#pragma unroll
        for (int off = 32; off >= 1; off >>= 1)
            p += __shfl_xor(p, off, 64);            // row score on every lane

        if (lane == 0) scores[b * NS + s] = p;

        if (p > m) {                                // wave-uniform branch
            const float sc = __expf(m - p);
            l *= sc;
#pragma unroll
            for (int k = 0; k < 4; ++k) ctx[k] *= sc;
            m = p;
        }
        const float w = __expf(p - m);
        l += w;
#pragma unroll
        for (int k = 0; k < 4; ++k) ctx[k] += w * e[k];
    }

    // ---- combine 4 waves -> one partial per block ----
    __shared__ float sml[NWAVES][2];
    __shared__ float sctx[NWAVES][NH];              // 16 KiB

    if (lane == 0) { sml[wave][0] = m; sml[wave][1] = l; }
    __syncthreads();

    const float M = fmaxf(fmaxf(sml[0][0], sml[1][0]), fmaxf(sml[2][0], sml[3][0]));
    float L = 0.f;
#pragma unroll
    for (int wv = 0; wv < NWAVES; ++wv)
        L += sml[wv][1] * __expf(sml[wv][0] - M);

    const float msc = __expf(m - M);                // wave-uniform
#pragma unroll
    for (int k = 0; k < 4; ++k) {
        f32x4 v = ctx[k] * msc;
        *reinterpret_cast<f32x4*>(&sctx[wave][lane * 4 + k * 256]) = v;
    }
    __syncthreads();

    float* outp = partials + (size_t)(b * NC + chunk) * PSTRIDE;
    for (int h = tid; h < NH; h += NTHREADS)
        outp[h] = sctx[0][h] + sctx[1][h] + sctx[2][h] + sctx[3][h];
    if (tid == 0) { outp[NH] = M; outp[NH + 1] = L; }

    // ---- last-block-per-batch finalize (threadfence-reduction pattern) ----
    __threadfence();                                 // release our partial+scores
    __syncthreads();
    __shared__ int s_last;
    if (tid == 0)
        s_last = (atomicAdd(&counters[b], 1) == NC - 1) ? 1 : 0;
    __syncthreads();
    if (!s_last) return;
    __threadfence();                                 // acquire others' writes

    const float* pb = partials + (size_t)b * NC * PSTRIDE;
    float Mg = -3.0e38f;
#pragma unroll
    for (int c = 0; c < NC; ++c)
        Mg = fmaxf(Mg, pb[c * PSTRIDE + NH]);

    float scale[NC];
    float Lg = 0.f;
#pragma unroll
    for (int c = 0; c < NC; ++c) {
        scale[c] = __expf(pb[c * PSTRIDE + NH] - Mg);
        Lg += pb[c * PSTRIDE + NH + 1] * scale[c];
    }
    const float invL = 1.0f / Lg;

    float* ob = out + (size_t)b * 2 * NH;
    for (int h = tid; h < NH; h += NTHREADS) {
        float acc = 0.f;
#pragma unroll
        for (int c = 0; c < NC; ++c)
            acc += pb[c * PSTRIDE + h] * scale[c];
        ob[h]      = acc * invL;                     // context
        ob[NH + h] = decb[h];                        // dec passthrough
    }

    float* wb = out + (size_t)NB * 2 * NH + (size_t)b * NS;
    const float* sc = scores + (size_t)b * NS;
    for (int s = tid; s < NS; s += NTHREADS)
        wb[s] = __expf(sc[s] - Mg) * invL;           // weights
}

// ---------------- proven two-kernel fallback (ws too small for counters) ----
__global__ __launch_bounds__(NTHREADS)
void dotattn_pass_a(const float* __restrict__ enc, const float* __restrict__ dec,
                    float* __restrict__ scores, float* __restrict__ partials)
{
    const int blk   = blockIdx.x;
    const int b     = blk >> 4;
    const int chunk = blk & (NC - 1);
    const int tid   = threadIdx.x;
    const int lane  = tid & 63;
    const int wave  = tid >> 6;

    const float* decb = dec + b * NH;
    f32x4 dreg[4];
#pragma unroll
    for (int k = 0; k < 4; ++k)
        dreg[k] = *reinterpret_cast<const f32x4*>(decb + lane * 4 + k * 256);

    f32x4 ctx[4];
#pragma unroll
    for (int k = 0; k < 4; ++k) ctx[k] = (f32x4){0.f, 0.f, 0.f, 0.f};
    float m = -3.0e38f, l = 0.f;

    const int start = chunk * ROWS;
    const float* encb = enc + (size_t)b * NS * NH;

    f32x4 en[4];
    {
        const size_t base = (size_t)(start + wave) * NH + lane * 4;
#pragma unroll
        for (int k = 0; k < 4; ++k) en[k] = nt_load4(encb + base + k * 256);
    }

    for (int s = start + wave; s < start + ROWS; s += NWAVES) {
        f32x4 e[4];
#pragma unroll
        for (int k = 0; k < 4; ++k) e[k] = en[k];
        if (s + NWAVES < start + ROWS) {
            const size_t nbase = (size_t)(s + NWAVES) * NH + lane * 4;
#pragma unroll
            for (int k = 0; k < 4; ++k) en[k] = nt_load4(encb + nbase + k * 256);
        }
        f32x4 p4 = e[0] * dreg[0];
#pragma unroll
        for (int k = 1; k < 4; ++k) p4 += e[k] * dreg[k];
        float p = p4.x + p4.y + p4.z + p4.w;
#pragma unroll
        for (int off = 32; off >= 1; off >>= 1) p += __shfl_xor(p, off, 64);
        if (lane == 0) scores[b * NS + s] = p;
        if (p > m) {
            const float sc = __expf(m - p);
            l *= sc;
#pragma unroll
            for (int k = 0; k < 4; ++k) ctx[k] *= sc;
            m = p;
        }
        const float w = __expf(p - m);
        l += w;
#pragma unroll
        for (int k = 0; k < 4; ++k) ctx[k] += w * e[k];
    }

    __shared__ float sml[NWAVES][2];
    __shared__ float sctx[NWAVES][NH];
    if (lane == 0) { sml[wave][0] = m; sml[wave][1] = l; }
    __syncthreads();
    const float M = fmaxf(fmaxf(sml[0][0], sml[1][0]), fmaxf(sml[2][0], sml[3][0]));
    float L = 0.f;
#pragma unroll
    for (int wv = 0; wv < NWAVES; ++wv) L += sml[wv][1] * __expf(sml[wv][0] - M);
    const float msc = __expf(m - M);
#pragma unroll
    for (int k = 0; k < 4; ++k) {
        f32x4 v = ctx[k] * msc;
        *reinterpret_cast<f32x4*>(&sctx[wave][lane * 4 + k * 256]) = v;
    }
    __syncthreads();
    float* outp = partials + (size_t)(b * NC + chunk) * PSTRIDE;
    for (int h = tid; h < NH; h += NTHREADS)
        outp[h] = sctx[0][h] + sctx[1][h] + sctx[2][h] + sctx[3][h];
    if (tid == 0) { outp[NH] = M; outp[NH + 1] = L; }
}

__global__ __launch_bounds__(NTHREADS)
void dotattn_finalize(const float* __restrict__ dec, const float* __restrict__ scores,
                      const float* __restrict__ partials, float* __restrict__ out)
{
    const int b   = blockIdx.x >> 2;
    const int q   = blockIdx.x & 3;
    const int tid = threadIdx.x;
    const float* pb = partials + (size_t)b * NC * PSTRIDE;

    float M = -3.0e38f;
#pragma unroll
    for (int c = 0; c < NC; ++c) M = fmaxf(M, pb[c * PSTRIDE + NH]);
    float scale[NC];
    float L = 0.f;
#pragma unroll
    for (int c = 0; c < NC; ++c) {
        scale[c] = __expf(pb[c * PSTRIDE + NH] - M);
        L += pb[c * PSTRIDE + NH + 1] * scale[c];
    }
    const float invL = 1.0f / L;

    {
        const int h = q * 256 + tid;
        float acc = 0.f;
#pragma unroll
        for (int c = 0; c < NC; ++c) acc += pb[c * PSTRIDE + h] * scale[c];
        float* ob = out + (size_t)b * 2 * NH;
        ob[h]      = acc * invL;
        ob[NH + h] = dec[b * NH + h];
    }
    const float* sc = scores + (size_t)b * NS + q * 1024;
    float* wb = out + (size_t)NB * 2 * NH + (size_t)b * NS + q * 1024;
    for (int s = tid; s < 1024; s += NTHREADS)
        wb[s] = __expf(sc[s] - M) * invL;
}

extern "C" void kernel_launch(void* const* d_in, const int* in_sizes, int n_in,
                              void* d_out, int out_size, void* d_ws, size_t ws_size,
                              hipStream_t stream)
{
    // Disambiguate inputs by element count (dec = 65536, enc = 268435456).
    const float* enc;
    const float* dec;
    if (in_sizes[0] == NB * NH) {
        dec = (const float*)d_in[0];
        enc = (const float*)d_in[1];
    } else {
        enc = (const float*)d_in[0];
        dec = (const float*)d_in[1];
    }
    float* out = (float*)d_out;

    // ws layout: counters int[64] | scores f32[64*4096] | partials f32[64*16*1026]
    const size_t cnt_bytes   = 256;                       // 64 ints
    const size_t score_bytes = (size_t)NB * NS * 4;       // 1 MiB
    const size_t part_bytes  = (size_t)NB * NC * PSTRIDE * 4;
    int*   counters = (int*)d_ws;
    float* scores   = (float*)((char*)d_ws + cnt_bytes);
    float* partials = (float*)((char*)d_ws + cnt_bytes + score_bytes);

    if (ws_size >= cnt_bytes + score_bytes + part_bytes) {
        hipMemsetAsync(counters, 0, cnt_bytes, stream);   // reset per call
        dotattn_fused<<<NB * NC, NTHREADS, 0, stream>>>(enc, dec, scores, partials,
                                                        counters, out);
    } else {
        // proven two-kernel fallback (no counters needed)
        float* scores2   = (float*)d_ws;
        float* partials2 = scores2 + (size_t)NB * NS;
        dotattn_pass_a<<<NB * NC, NTHREADS, 0, stream>>>(enc, dec, scores2, partials2);
        dotattn_finalize<<<NB * 4, NTHREADS, 0, stream>>>(dec, scores2, partials2, out);
    }
}

// Round 8
// 174.473 us; speedup vs baseline: 2.0729x; 2.0729x over previous
//
#include <hip/hip_runtime.h>
#include <hip/hip_bf16.h>

// DotAttention: B=64, S=4096, H=1024, f32 inputs, f32 outputs.
// out layout (flat f32): [B, 2H] concat(context, dec)  then  [B, S] weights.
//
// Round-5 structure (proven 202.4 us) with exactly ONE change: enc loads are
// non-temporal (evict-first) — the 1 GB read-once stream gets no reuse from
// L2/LLC, so skip allocation churn. Single-variable A/B vs round 5.
//
//   pass_a  : per (b, chunk) -> partial (ctx[H], m, l) + raw scores  (1024 blocks)
//             2-row unrolled, 8 VMEM in flight/lane.
//   finalize: merge 16 partials per batch, emit f32 outputs          (256 blocks)

#define NB 64
#define NS 4096
#define NH 1024
#define CHUNKS 16
#define ROWS (NS / CHUNKS)            // 256 rows per block
#define NTHREADS 256
#define NWAVES 4
#define PAIRS (ROWS / (NWAVES * 2))   // 32 row-pairs per wave
#define PSTRIDE (NH + 2)              // ctx[NH], m, l

typedef float f32x4 __attribute__((ext_vector_type(4)));

__device__ __forceinline__ f32x4 nt_load4(const float* p) {
    return __builtin_nontemporal_load(reinterpret_cast<const f32x4*>(p));
}

__global__ __launch_bounds__(NTHREADS)
void dotattn_pass_a(const float* __restrict__ enc, const float* __restrict__ dec,
                    float* __restrict__ scores, float* __restrict__ partials)
{
    const int blk   = blockIdx.x;
    const int b     = blk >> 4;    // / CHUNKS
    const int chunk = blk & 15;    // % CHUNKS
    const int tid   = threadIdx.x;
    const int lane  = tid & 63;
    const int wave  = tid >> 6;

    // Lane owns h-slice {lane*4 + k*256 + j : k,j in 0..3} (16 of 1024).
    const float* decb = dec + b * NH;
    f32x4 dreg[4];
#pragma unroll
    for (int k = 0; k < 4; ++k)
        dreg[k] = *reinterpret_cast<const f32x4*>(decb + lane * 4 + k * 256);

    f32x4 ctx[4];
#pragma unroll
    for (int k = 0; k < 4; ++k) ctx[k] = (f32x4){0.f, 0.f, 0.f, 0.f};
    float m = -3.0e38f, l = 0.f;

    const int s0 = chunk * ROWS;
    const float* encb = enc + (size_t)b * NS * NH;

    // Wave processes row pairs: s(i) = s0 + 8*i + 2*wave, s(i)+1.
    f32x4 en0[4], en1[4];
    {
        const size_t base = (size_t)(s0 + 2 * wave) * NH + lane * 4;
#pragma unroll
        for (int k = 0; k < 4; ++k) {
            en0[k] = nt_load4(encb + base + k * 256);
            en1[k] = nt_load4(encb + base + NH + k * 256);
        }
    }

    for (int i = 0; i < PAIRS; ++i) {
        const int s = s0 + 8 * i + 2 * wave;
        f32x4 e0[4], e1[4];
#pragma unroll
        for (int k = 0; k < 4; ++k) { e0[k] = en0[k]; e1[k] = en1[k]; }

        if (i + 1 < PAIRS) {                       // prefetch next pair (NT)
            const size_t nbase = (size_t)(s + 8) * NH + lane * 4;
#pragma unroll
            for (int k = 0; k < 4; ++k) {
                en0[k] = nt_load4(encb + nbase + k * 256);
                en1[k] = nt_load4(encb + nbase + NH + k * 256);
            }
        }

        f32x4 q0 = e0[0] * dreg[0];
        f32x4 q1 = e1[0] * dreg[0];
#pragma unroll
        for (int k = 1; k < 4; ++k) {
            q0 += e0[k] * dreg[k];
            q1 += e1[k] * dreg[k];
        }
        float p0 = q0.x + q0.y + q0.z + q0.w;
        float p1 = q1.x + q1.y + q1.z + q1.w;

        // two independent butterflies, interleaved by the scheduler
#pragma unroll
        for (int off = 32; off >= 1; off >>= 1) {
            p0 += __shfl_xor(p0, off, 64);
            p1 += __shfl_xor(p1, off, 64);
        }

        if (lane == 0)
            *reinterpret_cast<float2*>(&scores[b * NS + s]) = make_float2(p0, p1);

        const float pm = fmaxf(p0, p1);
        if (pm > m) {                               // wave-uniform, rare
            const float sc = __expf(m - pm);
            l *= sc;
#pragma unroll
            for (int k = 0; k < 4; ++k) ctx[k] *= sc;
            m = pm;
        }
        const float w0 = __expf(p0 - m);
        const float w1 = __expf(p1 - m);
        l += w0 + w1;
#pragma unroll
        for (int k = 0; k < 4; ++k)                 // reuse enc rows in-register
            ctx[k] += w0 * e0[k] + w1 * e1[k];
    }

    // ---- combine 4 waves -> one partial per block ----
    __shared__ float sml[NWAVES][2];
    __shared__ float sctx[NWAVES][NH];             // 16 KiB

    if (lane == 0) { sml[wave][0] = m; sml[wave][1] = l; }
    __syncthreads();

    const float M = fmaxf(fmaxf(sml[0][0], sml[1][0]), fmaxf(sml[2][0], sml[3][0]));
    float L = 0.f;
#pragma unroll
    for (int wv = 0; wv < NWAVES; ++wv)
        L += sml[wv][1] * __expf(sml[wv][0] - M);

    const float msc = __expf(m - M);               // wave-uniform
#pragma unroll
    for (int k = 0; k < 4; ++k) {
        f32x4 v = ctx[k] * msc;
        *reinterpret_cast<f32x4*>(&sctx[wave][lane * 4 + k * 256]) = v;
    }
    __syncthreads();

    float* outp = partials + (size_t)(b * CHUNKS + chunk) * PSTRIDE;
    for (int h = tid; h < NH; h += NTHREADS)
        outp[h] = sctx[0][h] + sctx[1][h] + sctx[2][h] + sctx[3][h];
    if (tid == 0) { outp[NH] = M; outp[NH + 1] = L; }
}

__global__ __launch_bounds__(NTHREADS)
void dotattn_finalize(const float* __restrict__ dec, const float* __restrict__ scores,
                      const float* __restrict__ partials, float* __restrict__ out)
{
    const int b   = blockIdx.x >> 2;               // batch
    const int q   = blockIdx.x & 3;                // quarter
    const int tid = threadIdx.x;
    const float* pb = partials + (size_t)b * CHUNKS * PSTRIDE;

    float M = -3.0e38f;
#pragma unroll
    for (int c = 0; c < CHUNKS; ++c)
        M = fmaxf(M, pb[c * PSTRIDE + NH]);

    float scale[CHUNKS];
    float L = 0.f;
#pragma unroll
    for (int c = 0; c < CHUNKS; ++c) {
        scale[c] = __expf(pb[c * PSTRIDE + NH] - M);
        L += pb[c * PSTRIDE + NH + 1] * scale[c];
    }
    const float invL = 1.0f / L;

    // context + dec quarter: h in [q*256, q*256+256)
    {
        const int h = q * 256 + tid;
        float acc = 0.f;
#pragma unroll
        for (int c = 0; c < CHUNKS; ++c)
            acc += pb[c * PSTRIDE + h] * scale[c];
        float* ob = out + (size_t)b * 2 * NH;
        ob[h]      = acc * invL;                    // context
        ob[NH + h] = dec[b * NH + h];               // dec passthrough
    }

    // weights quarter: s in [q*1024, q*1024+1024)
    const float* sc = scores + (size_t)b * NS + q * 1024;
    float* wb = out + (size_t)NB * 2 * NH + (size_t)b * NS + q * 1024;
    for (int s = tid; s < 1024; s += NTHREADS)
        wb[s] = __expf(sc[s] - M) * invL;
}

extern "C" void kernel_launch(void* const* d_in, const int* in_sizes, int n_in,
                              void* d_out, int out_size, void* d_ws, size_t ws_size,
                              hipStream_t stream)
{
    // Disambiguate inputs by element count (dec = 65536, enc = 268435456).
    const float* enc;
    const float* dec;
    if (in_sizes[0] == NB * NH) {
        dec = (const float*)d_in[0];
        enc = (const float*)d_in[1];
    } else {
        enc = (const float*)d_in[0];
        dec = (const float*)d_in[1];
    }
    float* out = (float*)d_out;

    // ws: scores f32[64*4096] (1 MiB) + partials f32[64*16*(1024+2)] (~4.2 MiB)
    float* scores   = (float*)d_ws;
    float* partials = scores + (size_t)NB * NS;

    dotattn_pass_a<<<NB * CHUNKS, NTHREADS, 0, stream>>>(enc, dec, scores, partials);
    dotattn_finalize<<<NB * 4, NTHREADS, 0, stream>>>(dec, scores, partials, out);
}